// Round 7
// baseline (108.087 us; speedup 1.0000x reference)
//
#include <hip/hip_runtime.h>

// Fused LSTM B=16384, T=60, IN=1, H=50, OUT=1 — wave-autonomous MFMA.
// 1024 blocks x 64 threads: one WAVE owns 16 batches and all 13 M-tiles
// (208 real gate rows; R4-R6 used 16 tiles = 23% waste). NO barriers:
// h-exchange is intra-wave via a custom K-permutation of the MFMA:
//   unit(k) = 8*(k>>3) + 4*(k&1) + ((k>>1)&3)   (k=0..55; 62=bias, 63=x)
// so lane (g,cl)'s 13 h-values (units 4T+g) pack into 7 half2 dwords that
// land exactly at next step's B-fragment positions: 7 ds_write_b32 +
// 2 ds_read_b128 per step, ordered by s_waitcnt lgkmcnt(0)+sched_barrier.
// Nonlinearities: batched reciprocal (1 rcp for the 4 gates, exact algebra)
// -> 7 trans/unit instead of 10. A-frags fp16 in VGPRs (104 regs), c fp32.

namespace {
constexpr int TS = 60;

typedef _Float16 half8 __attribute__((ext_vector_type(8)));
typedef _Float16 half2v __attribute__((ext_vector_type(2)));
typedef float f32x4 __attribute__((ext_vector_type(4)));

__device__ __forceinline__ float fexp2(float x) { return __builtin_amdgcn_exp2f(x); }
__device__ __forceinline__ float frcp(float x) { return __builtin_amdgcn_rcpf(x); }
__device__ __forceinline__ f32x4 mfma16(half8 a, half8 b, f32x4 c) {
  return __builtin_amdgcn_mfma_f32_16x16x32_f16(a, b, c, 0, 0, 0);
}
}  // namespace

__global__ __launch_bounds__(64, 1) void lstm_wv(
    const float* __restrict__ x,      // [B][60]
    const float* __restrict__ w_ih,   // [200]
    const float* __restrict__ w_hh,   // [200][50]
    const float* __restrict__ b_ih,   // [200]
    const float* __restrict__ b_hh,   // [200]
    const float* __restrict__ w_lin,  // [3000]
    const float* __restrict__ b_lin,  // [1]
    float* __restrict__ out)          // [B]
{
  __shared__ unsigned HB[2][16 * 32];  // 2 x 2 KB, [row=cl][32 dwords] swz
  __shared__ float WLT[4 * 13 * 60];   // 12.5 KB, [g][T][t]
  __shared__ float XL[TS * 16];        // 3.75 KB, [t][cl]

  const int lane = threadIdx.x;
  const int g = lane >> 4;   // k-group / unit residue
  const int cl = lane & 15;  // batch-in-wave; A-frag M-row
  const int s8 = cl & 7;
  const long bbase = (long)blockIdx.x * 16;

  // ---- stage XL[t][b] (coalesced global read) ----
  for (int i = lane; i < TS * 16; i += 64) {
    const int b = i / TS, t = i - b * TS;
    XL[t * 16 + b] = x[bbase * TS + i];
  }
  // ---- stage WLT[g][T][t] = w_lin[t*50 + 4T+g] (0 if unit >= 50) ----
  for (int i = lane; i < 4 * 13 * TS; i += 64) {
    const int gg = i / (13 * TS), rem = i - gg * (13 * TS);
    const int T = rem / TS, t = rem - T * TS;
    const int u = 4 * T + gg;
    WLT[i] = (u < 50) ? w_lin[t * 50 + u] : 0.0f;
  }
  // ---- zero both H buffers ----
  for (int i = lane; i < 1024; i += 64) ((unsigned*)HB)[i] = 0u;

  // ---- gather A-fragments from global (fp32 -> fp16), once ----
  // M-row = cl -> orig row = (cl&3)*50 + 4T + (cl>>2) (gate-major rows).
  // k-slot e of chunk kc: k = 32kc + 8g + e; unit via the K-permutation.
  half8 A[13][2];
  {
    const int gate = cl & 3, ur = cl >> 2;
#pragma unroll
    for (int T = 0; T < 13; ++T) {
      const int uA = 4 * T + ur;
      const int orig = gate * 50 + uA;
      const bool valid = (uA < 50);
#pragma unroll
      for (int kc = 0; kc < 2; ++kc) {
        half8 frag;
#pragma unroll
        for (int e = 0; e < 8; ++e) {
          const int k = kc * 32 + 8 * g + e;
          const int j = k >> 3, s = (k >> 1) & 3, cb = k & 1;
          float v = 0.0f;
          if (valid) {
            if (j <= 6) {
              const int u = 8 * j + 4 * cb + s;
              if (u < 50) v = w_hh[orig * 50 + u];
            } else if (k == 62) {
              v = b_ih[orig] + b_hh[orig];
            } else if (k == 63) {
              v = w_ih[orig];
            }
          }
          frag[e] = (_Float16)v;
        }
        A[T][kc] = frag;
      }
    }
  }

  // wave-internal fence: XL/HB zero visible to all lanes
  asm volatile("s_waitcnt lgkmcnt(0)" ::: "memory");
  __builtin_amdgcn_sched_barrier(0);

  // ---- buf0 specials: chunk 7, dword offset 3 = (1.0, x_0) ----
  const int rowb = cl * 32;
  const int clg = rowb + g;
  if (g == 3) {
    const half2v sp = {(_Float16)1.0f, (_Float16)XL[cl]};
    HB[0][clg + ((7 ^ s8) << 2)] = __builtin_bit_cast(unsigned, sp);
  }
  // (same-lane write->read; per-thread ordering suffices, chunk7 read by g==3 only)

  const unsigned b0off = rowb + ((g ^ s8) << 2);        // B kc=0: chunk g
  const unsigned b1off = rowb + (((4 | g) ^ s8) << 2);  // B kc=1: chunk 4+g
  const float* wlb = &WLT[g * 13 * TS];

  float c[13];
#pragma unroll
  for (int T = 0; T < 13; ++T) c[T] = 0.0f;
  float oacc = 0.0f;

  constexpr float L1 = 1.4426950408889634f;   // log2(e)
  constexpr float L2 = 2.8853901817779268f;   // 2*log2(e) (tanh arg)

#pragma unroll 1
  for (int t = 0; t < TS; ++t) {
    const unsigned* HR = HB[t & 1];
    unsigned* HW = HB[(t & 1) ^ 1];
    const half8 B0 = *(const half8*)&HR[b0off];
    const half8 B1 = *(const half8*)&HR[b1off];

    f32x4 d[13];
#pragma unroll
    for (int T = 0; T < 13; ++T) {
      f32x4 a = {0.f, 0.f, 0.f, 0.f};
      a = mfma16(A[T][0], B0, a);
      a = mfma16(A[T][1], B1, a);
      d[T] = a;
    }

    _Float16 hh[14];
    hh[13] = (_Float16)0.0f;  // pad (k-units 52..55)
#pragma unroll
    for (int T = 0; T < 13; ++T) {
      // batched reciprocal: 1 rcp for sigmoid(i), sigmoid(f), sigmoid(o),
      // tanh(g). sigm(x)=1/(1+2^(-L1 x)); tanh(x)=1-2/(1+2^(L2 x)).
      const float E1 = fexp2(-L1 * d[T][0]);
      const float E2 = fexp2(-L1 * d[T][1]);
      const float E3 = fexp2(-L1 * d[T][3]);
      const float E4 = fexp2(L2 * d[T][2]);
      const float P1 = 1.0f + E1, P2 = 1.0f + E2;
      const float P3 = 1.0f + E3, P4 = 1.0f + E4;
      const float p12 = P1 * P2, p34 = P3 * P4;
      const float r = frcp(p12 * p34);
      const float r12 = r * p34, r34 = r * p12;
      const float si = r12 * P2, sf = r12 * P1;
      const float so = r34 * P4;
      const float tg = fmaf(-2.0f, r34 * P3, 1.0f);
      const float cn = fmaf(sf, c[T], si * tg);
      c[T] = cn;
      const float Ec = fexp2(L2 * cn);
      const float tc = fmaf(-2.0f, frcp(1.0f + Ec), 1.0f);
      const float hn = so * tc;
      oacc = fmaf(hn, wlb[T * TS + t], oacc);
      hh[T] = (_Float16)hn;
    }

    // ---- pack & write: hpack[j]=(h[2j],h[2j+1]) -> dword (chunk j^s8, ofs g)
#pragma unroll
    for (int j = 0; j < 7; ++j) {
      const half2v hp = {hh[2 * j], hh[2 * j + 1]};
      HW[clg + ((j ^ s8) << 2)] = __builtin_bit_cast(unsigned, hp);
    }
    if (g == 3) {  // specials for next step: k=62 -> 1.0, k=63 -> x_{t+1}
      const int tn = (t + 1 < TS) ? (t + 1) : (TS - 1);
      const half2v sp = {(_Float16)1.0f, (_Float16)XL[tn * 16 + cl]};
      HW[clg + ((7 ^ s8) << 2)] = __builtin_bit_cast(unsigned, sp);
    }
    asm volatile("s_waitcnt lgkmcnt(0)" ::: "memory");
    __builtin_amdgcn_sched_barrier(0);
  }

  // ---- reduce oacc over the 4 g-groups (units split by g) ----
  oacc += __shfl_xor(oacc, 32);
  oacc += __shfl_xor(oacc, 16);
  if (lane < 16) out[bbase + lane] = oacc + b_lin[0];
}

extern "C" void kernel_launch(void* const* d_in, const int* in_sizes, int n_in,
                              void* d_out, int out_size, void* d_ws, size_t ws_size,
                              hipStream_t stream) {
  const float* x     = (const float*)d_in[0];
  const float* w_ih  = (const float*)d_in[1];
  const float* w_hh  = (const float*)d_in[2];
  const float* b_ih  = (const float*)d_in[3];
  const float* b_hh  = (const float*)d_in[4];
  const float* w_lin = (const float*)d_in[5];
  const float* b_lin = (const float*)d_in[6];
  float* out = (float*)d_out;

  dim3 grid(16384 / 16);  // 1024 single-wave blocks
  dim3 block(64);
  lstm_wv<<<grid, block, 0, stream>>>(x, w_ih, w_hh, b_ih, b_hh, w_lin,
                                      b_lin, out);
}

// Round 8
// 99.781 us; speedup vs baseline: 1.0832x; 1.0832x over previous
//
#include <hip/hip_runtime.h>

// Fused LSTM B=16384, T=60, IN=1, H=50, OUT=1 — 8-wave dual-group MFMA.
// 512 blocks x 512 thr (8 waves, launch_bounds(512,4) -> 2 blocks/CU =
// 4 waves/SIMD). Block owns 32 batches = two independent 16-batch groups.
// Wave wv owns M-tiles {2wv, 2wv+1} for BOTH groups: per wave/step only
// 8 MFMA + 28 trans + ~90 VALU (short critical path), and its 2 units per
// lane are k-adjacent -> h-write is ONE ds_write_b32 per group. Batched
// 4-term reciprocal nonlinearity (exact algebra, R7-verified). Weights fp16
// (hi) in VGPRs; unit = 16g+T; K-cols 0..49=h, 62=1(bias), 63=x; H fp16
// [row=cl][64] chunk-XOR-swizzled, double-buffered, 1 barrier/step.
// R4-R7 evidence: stall-bound (wall 4000cy/step vs ~1800 issue) -> this
// round maximizes waves/SIMD while shrinking per-wave chain.

namespace {
constexpr int TS = 60;

typedef _Float16 half8 __attribute__((ext_vector_type(8)));
typedef _Float16 half2v __attribute__((ext_vector_type(2)));
typedef float f32x4 __attribute__((ext_vector_type(4)));
typedef float f32x2 __attribute__((ext_vector_type(2)));

__device__ __forceinline__ float fexp2(float x) { return __builtin_amdgcn_exp2f(x); }
__device__ __forceinline__ float frcp(float x) { return __builtin_amdgcn_rcpf(x); }
__device__ __forceinline__ f32x4 mfma16(half8 a, half8 b, f32x4 c) {
  return __builtin_amdgcn_mfma_f32_16x16x32_f16(a, b, c, 0, 0, 0);
}
}  // namespace

__global__ __launch_bounds__(512, 4) void lstm_w8x2(
    const float* __restrict__ x,      // [B][60]
    const float* __restrict__ w_ih,   // [200]
    const float* __restrict__ w_hh,   // [200][50]
    const float* __restrict__ b_ih,   // [200]
    const float* __restrict__ b_hh,   // [200]
    const float* __restrict__ w_lin,  // [3000]
    const float* __restrict__ b_lin,  // [1]
    float* __restrict__ out)          // [B]
{
  __shared__ unsigned Hs[2][2][512];  // [grp][buf][row=cl*32 + dword]  8 KB
  __shared__ float WL[TS * 64];       // 15.36 KB, 0-padded
  __shared__ float XL[TS * 32];       // 7.68 KB [t][b 0..31]
  __shared__ float OB[8][2][16];      // 1 KB

  const int tid = threadIdx.x;
  const int lane = tid & 63;
  const int wv = tid >> 6;   // 0..7
  const int g = lane >> 4;   // lane quad-group
  const int cl = lane & 15;  // batch-in-group; A-frag M-row
  const int s8 = cl & 7;
  const long bbase = (long)blockIdx.x * 32;

  // ---- stage XL[t][b] (coalesced over block's 32x60 slice) ----
  for (int i = tid; i < TS * 32; i += 512) {
    const int b = i / TS, t = i - b * TS;
    XL[t * 32 + b] = x[bbase * TS + i];
  }
  // ---- stage WL[t][u] (u<50 else 0) ----
  for (int i = tid; i < TS * 64; i += 512) {
    const int t = i >> 6, u = i & 63;
    WL[i] = (u < 50) ? w_lin[t * 50 + u] : 0.0f;
  }
  // ---- zero all 4 H buffers ----
  for (int i = tid; i < 2048; i += 512) ((unsigned*)Hs)[i] = 0u;

  // ---- gather this wave's A-fragments (tiles 2wv, 2wv+1), once ----
  // tile T row cl -> orig gate row (cl&3)*50 + 16*(cl>>2) + T;
  // element e of chunk kc -> k = 32kc + 8g + e (k<50: h_k; 62: bias; 63: x).
  half8 A[2][2];
  {
    const int gate = cl & 3, ur = cl >> 2;
#pragma unroll
    for (int tau = 0; tau < 2; ++tau) {
      const int T = 2 * wv + tau;
      const int uA = 16 * ur + T;
      const int orig = gate * 50 + uA;
      const bool valid = (uA < 50);
#pragma unroll
      for (int kc = 0; kc < 2; ++kc) {
        half8 frag;
#pragma unroll
        for (int e = 0; e < 8; ++e) {
          const int k = kc * 32 + 8 * g + e;
          float v = 0.0f;
          if (valid) {
            if (k < 50) v = w_hh[orig * 50 + k];
            else if (k == 62) v = b_ih[orig] + b_hh[orig];
            else if (k == 63) v = w_ih[orig];
          }
          frag[e] = (_Float16)v;
        }
        A[tau][kc] = frag;
      }
    }
  }
  __syncthreads();

  // ---- specials in buf0: k=62,63 = (1.0, x_0); chunk 7, dword 3 ----
  if (wv == 7 && g == 3) {
#pragma unroll
    for (int grp = 0; grp < 2; ++grp) {
      const half2v sp = {(_Float16)1.0f, (_Float16)XL[grp * 16 + cl]};
      Hs[grp][0][cl * 32 + (((7 ^ s8) << 2) | 3)] =
          __builtin_bit_cast(unsigned, sp);
    }
  }
  __syncthreads();

  const int rowdw = cl * 32;
  const int rd0 = rowdw + ((g ^ s8) << 2);        // B kc=0: chunk g
  const int rd1 = rowdw + (((4 | g) ^ s8) << 2);  // B kc=1: chunk 4+g
  const int hw = 16 * g + 2 * wv;                 // this lane's write halves
  const int wd = rowdw + ((((hw >> 3) ^ s8) << 2) | ((hw & 7) >> 1));

  float c[2][2] = {{0.f, 0.f}, {0.f, 0.f}};  // [grp][tau]
  float oacc[2] = {0.f, 0.f};

  constexpr float L1 = 1.4426950408889634f;  // log2(e)
  constexpr float L2 = 2.8853900817779268f;  // 2*log2(e)

#pragma unroll 1
  for (int t = 0; t < TS; ++t) {
    const int p = t & 1;
    half8 B0[2], B1[2];
#pragma unroll
    for (int grp = 0; grp < 2; ++grp) {
      B0[grp] = *(const half8*)&Hs[grp][p][rd0];
      B1[grp] = *(const half8*)&Hs[grp][p][rd1];
    }
    f32x4 d[2][2];
#pragma unroll
    for (int grp = 0; grp < 2; ++grp) {
#pragma unroll
      for (int tau = 0; tau < 2; ++tau) {
        f32x4 a = {0.f, 0.f, 0.f, 0.f};
        a = mfma16(A[tau][0], B0[grp], a);
        a = mfma16(A[tau][1], B1[grp], a);
        d[grp][tau] = a;
      }
    }
    const f32x2 wl = *(const f32x2*)&WL[t * 64 + hw];

    half2v hh[2];
#pragma unroll
    for (int grp = 0; grp < 2; ++grp) {
#pragma unroll
      for (int tau = 0; tau < 2; ++tau) {
        // 4-term batched reciprocal: 1 rcp serves sigm(i),sigm(f),sigm(o),
        // tanh(g). sigm(x)=1/(1+2^(-L1 x)); tanh(x)=1-2/(1+2^(L2 x)).
        const float E1 = fexp2(-L1 * d[grp][tau][0]);
        const float E2 = fexp2(-L1 * d[grp][tau][1]);
        const float E3 = fexp2(-L1 * d[grp][tau][3]);
        const float E4 = fexp2(L2 * d[grp][tau][2]);
        const float P1 = 1.0f + E1, P2 = 1.0f + E2;
        const float P3 = 1.0f + E3, P4 = 1.0f + E4;
        const float p12 = P1 * P2, p34 = P3 * P4;
        const float r = frcp(p12 * p34);
        const float r12 = r * p34, r34 = r * p12;
        const float si = r12 * P2, sf = r12 * P1;
        const float so = r34 * P4;
        const float tg = fmaf(-2.0f, r34 * P3, 1.0f);
        const float cn = fmaf(sf, c[grp][tau], si * tg);
        c[grp][tau] = cn;
        const float Ec = fexp2(L2 * cn);
        const float tc = fmaf(-2.0f, frcp(1.0f + Ec), 1.0f);
        const float hn = so * tc;
        oacc[grp] = fmaf(hn, wl[tau], oacc[grp]);
        hh[grp][tau] = (_Float16)hn;
      }
    }

    if (wv == 7 && g == 3) {  // our halves are k=62,63 -> write specials
      const int tn = (t + 1 < TS) ? (t + 1) : (TS - 1);
      hh[0][0] = (_Float16)1.0f;
      hh[0][1] = (_Float16)XL[tn * 32 + cl];
      hh[1][0] = (_Float16)1.0f;
      hh[1][1] = (_Float16)XL[tn * 32 + 16 + cl];
    }
    Hs[0][p ^ 1][wd] = __builtin_bit_cast(unsigned, hh[0]);
    Hs[1][p ^ 1][wd] = __builtin_bit_cast(unsigned, hh[1]);
    __syncthreads();
  }

  // ---- reduce over g (shfl), then over waves (LDS) ----
  oacc[0] += __shfl_xor(oacc[0], 32);
  oacc[0] += __shfl_xor(oacc[0], 16);
  oacc[1] += __shfl_xor(oacc[1], 32);
  oacc[1] += __shfl_xor(oacc[1], 16);
  if (lane < 16) {
    OB[wv][0][cl] = oacc[0];
    OB[wv][1][cl] = oacc[1];
  }
  __syncthreads();
  if (tid < 32) {
    const int grp = tid >> 4, b = tid & 15;
    float s = b_lin[0];
#pragma unroll
    for (int q = 0; q < 8; ++q) s += OB[q][grp][b];
    out[bbase + grp * 16 + b] = s;
  }
}

extern "C" void kernel_launch(void* const* d_in, const int* in_sizes, int n_in,
                              void* d_out, int out_size, void* d_ws, size_t ws_size,
                              hipStream_t stream) {
  const float* x     = (const float*)d_in[0];
  const float* w_ih  = (const float*)d_in[1];
  const float* w_hh  = (const float*)d_in[2];
  const float* b_ih  = (const float*)d_in[3];
  const float* b_hh  = (const float*)d_in[4];
  const float* w_lin = (const float*)d_in[5];
  const float* b_lin = (const float*)d_in[6];
  float* out = (float*)d_out;

  dim3 grid(16384 / 32);  // 512 blocks -> 2 per CU, 4 waves/SIMD
  dim3 block(512);
  lstm_w8x2<<<grid, block, 0, stream>>>(x, w_ih, w_hh, b_ih, b_hh, w_lin,
                                        b_lin, out);
}